// Round 8
// baseline (1755.879 us; speedup 1.0000x reference)
//
#include <hip/hip_runtime.h>

// ---------------- problem constants ----------------
#define BATCH 8
#define TLEN  4096
#define DIM   768
#define TP    4098            // TLEN padded to multiple of WS=3
#define NWIN  1366            // TP/3
#define HEADS 48
#define HD    16
#define MREAL (BATCH*TP)      // 32784 rows in the rolled/padded sequence
#define MP    32896           // MREAL padded to 257*128 (GEMM tile multiple)
#define M2    (BATCH*TLEN)    // 32768 rows for the MLP path

typedef unsigned short u16;
typedef __bf16  bf16x8  __attribute__((ext_vector_type(8)));
typedef short   short8v __attribute__((ext_vector_type(8)));
typedef float   float4v __attribute__((ext_vector_type(4)));
typedef u16     u16x4   __attribute__((ext_vector_type(4)));

static __device__ __forceinline__ float bf2f(u16 u) {
  unsigned int x = ((unsigned int)u) << 16;
  return __builtin_bit_cast(float, x);
}
static __device__ __forceinline__ u16 f2bf(float f) {  // round-nearest-even
  unsigned int x = __builtin_bit_cast(unsigned int, f);
  x += 0x7fffu + ((x >> 16) & 1u);
  return (u16)(x >> 16);
}

static __device__ __forceinline__ float4v mfma_bf16(short8v a, short8v b, float4v c) {
  return __builtin_amdgcn_mfma_f32_16x16x32_bf16(
      __builtin_bit_cast(bf16x8, a), __builtin_bit_cast(bf16x8, b), c, 0, 0, 0);
}

static __device__ __forceinline__ void gload_lds16(const u16* src, u16* ldsdst) {
  __builtin_amdgcn_global_load_lds(
      (const __attribute__((address_space(1))) void*)src,
      (__attribute__((address_space(3))) void*)ldsdst,
      16, 0, 0);
}

// ---------------- weight convert + transpose: w[K][N] fp32 -> wt[N][K] bf16 ----
__global__ __launch_bounds__(256) void cvt_transpose(const float* __restrict__ w,
                                                     u16* __restrict__ wt,
                                                     int K, int N) {
  int idx = blockIdx.x * 256 + threadIdx.x;
  if (idx >= K * N) return;
  int k = idx / N, n = idx - k * N;
  wt[(size_t)n * K + k] = f2bf(w[idx]);
}

// ---------------- LayerNorm fp32-in (wave per row). ROLL: xs = roll(pad(LN(x)),-1) ----
template<bool ROLL>
__global__ __launch_bounds__(256) void ln_kernel(const float* __restrict__ x,
                                                 const float* __restrict__ g,
                                                 const float* __restrict__ bet,
                                                 u16* __restrict__ out) {
  int wave = threadIdx.x >> 6, lane = threadIdx.x & 63;
  int row = blockIdx.x * 4 + wave;
  u16* orow = out + (size_t)row * DIM;

  const float* src;
  if (ROLL) {
    bool zero = (row >= MREAL);
    int t = 0, b = 0;
    if (!zero) {
      b = row / TP;
      int m = row - b * TP;
      t = m + 1; if (t == TP) t = 0;      // xs[m] = xp[(m+1) % TP]
      if (t >= TLEN) zero = true;         // xp pad rows are exact zeros
    }
    if (zero) {
      u16x4 z = {};
#pragma unroll
      for (int c = 0; c < 3; ++c) *(u16x4*)&orow[c * 256 + lane * 4] = z;
      return;
    }
    src = x + ((size_t)b * TLEN + t) * DIM;
  } else {
    src = x + (size_t)row * DIM;
  }

  float v[12];
  float s = 0.f, s2 = 0.f;
#pragma unroll
  for (int c = 0; c < 3; ++c) {
    float4v f = *(const float4v*)&src[c * 256 + lane * 4];
#pragma unroll
    for (int q = 0; q < 4; ++q) { v[c * 4 + q] = f[q]; s += f[q]; s2 += f[q] * f[q]; }
  }
#pragma unroll
  for (int off = 1; off < 64; off <<= 1) {
    s  += __shfl_xor(s, off);
    s2 += __shfl_xor(s2, off);
  }
  float mean = s * (1.f / DIM);
  float var  = s2 * (1.f / DIM) - mean * mean;
  float rs   = rsqrtf(var + 1e-5f);
#pragma unroll
  for (int c = 0; c < 3; ++c) {
    int col = c * 256 + lane * 4;
    float4v gv = *(const float4v*)&g[col];
    float4v bv = *(const float4v*)&bet[col];
    u16x4 o4;
#pragma unroll
    for (int q = 0; q < 4; ++q) o4[q] = f2bf((v[c * 4 + q] - mean) * rs * gv[q] + bv[q]);
    *(u16x4*)&orow[col] = o4;
  }
}

// ---------------- LayerNorm bf16-in (wave per row), rows = M2 ----------------
__global__ __launch_bounds__(256) void lnb_kernel(const u16* __restrict__ xin,
                                                  const float* __restrict__ g,
                                                  const float* __restrict__ bet,
                                                  u16* __restrict__ out) {
  int wave = threadIdx.x >> 6, lane = threadIdx.x & 63;
  int row = blockIdx.x * 4 + wave;
  const u16* src = xin + (size_t)row * DIM;
  u16* orow = out + (size_t)row * DIM;

  float v[12];
  float s = 0.f, s2 = 0.f;
#pragma unroll
  for (int c = 0; c < 3; ++c) {
    u16x4 h = *(const u16x4*)&src[c * 256 + lane * 4];
#pragma unroll
    for (int q = 0; q < 4; ++q) {
      float f = bf2f(h[q]);
      v[c * 4 + q] = f; s += f; s2 += f * f;
    }
  }
#pragma unroll
  for (int off = 1; off < 64; off <<= 1) {
    s  += __shfl_xor(s, off);
    s2 += __shfl_xor(s2, off);
  }
  float mean = s * (1.f / DIM);
  float var  = s2 * (1.f / DIM) - mean * mean;
  float rs   = rsqrtf(var + 1e-5f);
#pragma unroll
  for (int c = 0; c < 3; ++c) {
    int col = c * 256 + lane * 4;
    float4v gv = *(const float4v*)&g[col];
    float4v bv = *(const float4v*)&bet[col];
    u16x4 o4;
#pragma unroll
    for (int q = 0; q < 4; ++q) o4[q] = f2bf((v[c * 4 + q] - mean) * rs * gv[q] + bv[q]);
    *(u16x4*)&orow[col] = o4;
  }
}

// ---------------- window attention: one thread per (window, head) ----------------
__global__ __launch_bounds__(256) void attn_kernel(const u16* __restrict__ qkv,
                                                   u16* __restrict__ o) {
  int gid = blockIdx.x * 256 + threadIdx.x;   // grid sized exactly
  int h = gid % HEADS;
  int w = gid / HEADS;
  int b = w / NWIN, wl = w - b * NWIN;
  size_t row0 = (size_t)b * TP + (size_t)wl * 3;

  float q[3][HD], k[3][HD];
#pragma unroll
  for (int t = 0; t < 3; ++t) {
    const u16* rp = qkv + (row0 + t) * (3 * DIM) + h * HD;
    short8v q0 = *(const short8v*)(rp);
    short8v q1 = *(const short8v*)(rp + 8);
    short8v k0 = *(const short8v*)(rp + DIM);
    short8v k1 = *(const short8v*)(rp + DIM + 8);
#pragma unroll
    for (int d = 0; d < 8; ++d) {
      q[t][d] = bf2f((u16)q0[d]); q[t][d + 8] = bf2f((u16)q1[d]);
      k[t][d] = bf2f((u16)k0[d]); k[t][d + 8] = bf2f((u16)k1[d]);
    }
  }
  float p[3][3];
#pragma unroll
  for (int i = 0; i < 3; ++i)
#pragma unroll
    for (int j = 0; j < 3; ++j) {
      float s = 0.f;
#pragma unroll
      for (int d = 0; d < HD; ++d) s += q[i][d] * k[j][d];
      p[i][j] = s * 0.25f;                 // HD^-0.5
    }
#pragma unroll
  for (int i = 0; i < 3; ++i) {
    float mx = fmaxf(p[i][0], fmaxf(p[i][1], p[i][2]));
    float e0 = __expf(p[i][0] - mx), e1 = __expf(p[i][1] - mx), e2 = __expf(p[i][2] - mx);
    float inv = 1.f / (e0 + e1 + e2);
    p[i][0] = e0 * inv; p[i][1] = e1 * inv; p[i][2] = e2 * inv;
  }
  float acc[3][HD];
#pragma unroll
  for (int i = 0; i < 3; ++i)
#pragma unroll
    for (int d = 0; d < HD; ++d) acc[i][d] = 0.f;
#pragma unroll
  for (int t = 0; t < 3; ++t) {
    const u16* rp = qkv + (row0 + t) * (3 * DIM) + 2 * DIM + h * HD;
    short8v v0 = *(const short8v*)(rp);
    short8v v1 = *(const short8v*)(rp + 8);
#pragma unroll
    for (int d = 0; d < 8; ++d) {
      float a = bf2f((u16)v0[d]), bb = bf2f((u16)v1[d]);
#pragma unroll
      for (int i = 0; i < 3; ++i) { acc[i][d] += p[i][t] * a; acc[i][d + 8] += p[i][t] * bb; }
    }
  }
#pragma unroll
  for (int i = 0; i < 3; ++i) {
    u16 tmp[HD];
#pragma unroll
    for (int d = 0; d < HD; ++d) tmp[d] = f2bf(acc[i][d]);
    u16* op = o + (row0 + i) * DIM + h * HD;
    *(short8v*)op = *(short8v*)tmp;
    *(short8v*)(op + 8) = *(short8v*)(tmp + 8);
  }
}

// ---------------- 128x128 MFMA GEMM, 8 waves, single buffer + overlapped stage --
// A[M][K] bf16, Bt[N][K] bf16. 512 threads (2M x 4N waves, wave tile 64x32).
// LDS 32 KiB single buffer. launch_bounds(512,6): VGPR cap 85 -> fits the
// 12-frag live set (r6's failure was the (512,8) cap 64 -> scratch spill),
// 3 blocks/CU residency (r4-proven).
// Per K-step: ds_read ALL 12 frags to regs -> lgkmcnt(0)+barrier (buffer dead)
// -> stage(t+1) into SAME buffer (hides under MFMAs + cross-block TLP)
// -> 16 MFMAs (regs only) -> vmcnt(0)+barrier (stage landed).
// XOR swizzle byte^=((row&7)<<4): inverse-swizzled global source (linear
// global_load_lds dest) + swizzled ds_read.
// EPI 0: C bf16 plain
// EPI 1: resf bf16 = x + scatter(roll)   (outb=resf, residf=x)
// EPI 2: bias+ReLU bf16
// EPI 3: out fp32 = resf + acc + bias    (outf=out, residb=resf)
template<int EPI>
__global__ __launch_bounds__(512, 6) void gemm8w(const u16* __restrict__ A,
                                                 const u16* __restrict__ Bt,
                                                 int N, int K,
                                                 u16* __restrict__ outb,
                                                 float* __restrict__ outf,
                                                 const float* __restrict__ residf,
                                                 const u16* __restrict__ residb,
                                                 const float* __restrict__ bias) {
  __shared__ u16 As[128 * 64];
  __shared__ u16 Bs[128 * 64];
  const int tid = threadIdx.x;
  const int wave = tid >> 6, lane = tid & 63;
  const int wm = wave >> 2, wn = wave & 3;          // 2 M-waves x 4 N-waves
  const int r = lane & 15, gq = lane >> 4;

  // bijective XCD chunk swizzle (m204) on linearized bid (x fastest)
  const int nwg = gridDim.x, gx = N >> 7;
  int wg = blockIdx.x;
  int qd = nwg >> 3, rr = nwg & 7, xcd = wg & 7, lid = wg >> 3;
  int swz = (xcd < rr ? xcd * (qd + 1) : rr * (qd + 1) + (xcd - rr) * qd) + lid;
  const int tm = swz / gx, tn = swz - tm * gx;
  const int arow0 = tm * 128, brow0 = tn * 128;

  // staging precompute: 2 chunks of 8 KiB per matrix; linear LDS dest
  // d = c*8192 + tid*16 bytes, global source column pre-swizzled (same XOR).
  int srow[2], scol[2];
#pragma unroll
  for (int c = 0; c < 2; ++c) {
    int d = c * 8192 + tid * 16;
    srow[c] = d >> 7;
    scol[c] = (((d & 127) ^ ((srow[c] & 7) << 4)) >> 1);
  }

  // fragment-read swizzled K-offsets (elements); row&7 == r&7 (bases mult of 16)
  const int kx0 = (((gq * 16) ^ ((r & 7) << 4)) >> 1);        // kk = 0
  const int kx1 = (((64 + gq * 16) ^ ((r & 7) << 4)) >> 1);   // kk = 1
  const int rA = wm * 64 + r, rB = wn * 32 + r;

  float4v acc[4][2];
#pragma unroll
  for (int i = 0; i < 4; ++i)
#pragma unroll
    for (int j = 0; j < 2; ++j) acc[i][j] = (float4v){0.f, 0.f, 0.f, 0.f};

  auto stage = [&](int tk) {   // 4 global_load_lds per thread, same buffer
#pragma unroll
    for (int c = 0; c < 2; ++c) {
      gload_lds16(A  + (size_t)(arow0 + srow[c]) * K + tk * 64 + scol[c],
                  &As[0] + c * 4096 + tid * 8);
      gload_lds16(Bt + (size_t)(brow0 + srow[c]) * K + tk * 64 + scol[c],
                  &Bs[0] + c * 4096 + tid * 8);
    }
  };

  const int NT = K >> 6;
  stage(0);
  asm volatile("s_waitcnt vmcnt(0)" ::: "memory");
  __builtin_amdgcn_sched_barrier(0);
  __builtin_amdgcn_s_barrier();       // tile 0 fully in LDS

  for (int t = 0; t < NT; ++t) {
    short8v af[8], bfr[4];
#pragma unroll
    for (int i = 0; i < 4; ++i) {
      af[2 * i]     = *(const short8v*)&As[(rA + i * 16) * 64 + kx0];
      af[2 * i + 1] = *(const short8v*)&As[(rA + i * 16) * 64 + kx1];
    }
#pragma unroll
    for (int j = 0; j < 2; ++j) {
      bfr[2 * j]     = *(const short8v*)&Bs[(rB + j * 16) * 64 + kx0];
      bfr[2 * j + 1] = *(const short8v*)&Bs[(rB + j * 16) * 64 + kx1];
    }
    asm volatile("s_waitcnt lgkmcnt(0)" ::: "memory");  // my frag reads complete
    __builtin_amdgcn_sched_barrier(0);
    __builtin_amdgcn_s_barrier();       // ALL waves done reading -> buffer dead
    __builtin_amdgcn_sched_barrier(0);

    if (t + 1 < NT) stage(t + 1);       // overwrite same buffer under MFMAs

    __builtin_amdgcn_s_setprio(1);
#pragma unroll
    for (int i = 0; i < 4; ++i)
#pragma unroll
      for (int j = 0; j < 2; ++j) {
        acc[i][j] = mfma_bf16(af[2 * i],     bfr[2 * j],     acc[i][j]);
        acc[i][j] = mfma_bf16(af[2 * i + 1], bfr[2 * j + 1], acc[i][j]);
      }
    __builtin_amdgcn_s_setprio(0);

    if (t + 1 < NT) {
      asm volatile("s_waitcnt vmcnt(0)" ::: "memory");  // my stage loads landed
      __builtin_amdgcn_sched_barrier(0);
      __builtin_amdgcn_s_barrier();     // everyone's stage landed & visible
      __builtin_amdgcn_sched_barrier(0);
    }
  }

  // epilogue: D mapping col=lane&15, row=(lane>>4)*4+reg  [m89-verified]
#pragma unroll
  for (int i = 0; i < 4; ++i) {
#pragma unroll
    for (int j = 0; j < 2; ++j) {
      int colg = brow0 + wn * 32 + j * 16 + r;
      int rowb = arow0 + wm * 64 + i * 16 + gq * 4;
#pragma unroll
      for (int v = 0; v < 4; ++v) {
        int rg = rowb + v;
        float val = acc[i][j][v];
        if constexpr (EPI == 0) {
          outb[(size_t)rg * N + colg] = f2bf(val);
        } else if constexpr (EPI == 1) {
          if (rg < MREAL) {
            int b = rg / TP, m = rg - b * TP;
            int t = m + 1; if (t == TP) t = 0;
            if (t < TLEN) {
              size_t idx = ((size_t)b * TLEN + t) * DIM + colg;
              outb[idx] = f2bf(residf[idx] + val);
            }
          }
        } else if constexpr (EPI == 2) {
          float z = val + bias[colg];
          outb[(size_t)rg * N + colg] = f2bf(z > 0.f ? z : 0.f);
        } else {
          size_t idx = (size_t)rg * N + colg;
          outf[idx] = bf2f(residb[idx]) + val + bias[colg];
        }
      }
    }
  }
}

// ---------------- host ----------------
extern "C" void kernel_launch(void* const* d_in, const int* in_sizes, int n_in,
                              void* d_out, int out_size, void* d_ws, size_t ws_size,
                              hipStream_t stream) {
  const float* x      = (const float*)d_in[0];
  const float* g1     = (const float*)d_in[1];
  const float* b1     = (const float*)d_in[2];
  const float* w_qkv  = (const float*)d_in[3];
  const float* w_proj = (const float*)d_in[4];
  const float* g2     = (const float*)d_in[5];
  const float* b2     = (const float*)d_in[6];
  const float* w_mlp1 = (const float*)d_in[7];
  const float* b_mlp1 = (const float*)d_in[8];
  const float* w_mlp2 = (const float*)d_in[9];
  const float* b_mlp2 = (const float*)d_in[10];
  float* out = (float*)d_out;

  // workspace layout (~262 MB total)
  u16* xs     = (u16*)d_ws;                        // MP*768 bf16 (LN1, rolled/padded)
  u16* qkv    = xs     + (size_t)MP * DIM;         // MP*2304 bf16
  u16* obuf   = qkv    + (size_t)MP * 3 * DIM;     // MP*768 bf16 (attn out)
  u16* wqkvT  = obuf   + (size_t)MP * DIM;         // [2304][768]
  u16* wprojT = wqkvT  + (size_t)3 * DIM * DIM;    // [768][768]
  u16* wm1T   = wprojT + (size_t)DIM * DIM;        // [1536][768]
  u16* wm2T   = wm1T   + (size_t)2 * DIM * DIM;    // [768][1536]
  // region reuse across the pipeline (each producer runs after the consumer
  // of the previous tenant):
  u16* resf = xs;    // M2*768  bf16 residual trunk (xs dead after QKV GEMM)
  u16* ln2o = obuf;  // M2*768  (obuf dead after proj GEMM)
  u16* h1   = qkv;   // M2*1536 (qkv dead after attn)

  cvt_transpose<<<(DIM * 3 * DIM + 255) / 256, 256, 0, stream>>>(w_qkv,  wqkvT,  DIM,     3 * DIM);
  cvt_transpose<<<(DIM * DIM + 255)     / 256, 256, 0, stream>>>(w_proj, wprojT, DIM,     DIM);
  cvt_transpose<<<(DIM * 2 * DIM + 255) / 256, 256, 0, stream>>>(w_mlp1, wm1T,   DIM,     2 * DIM);
  cvt_transpose<<<(2 * DIM * DIM + 255) / 256, 256, 0, stream>>>(w_mlp2, wm2T,   2 * DIM, DIM);

  ln_kernel<true><<<MP / 4, 256, 0, stream>>>(x, g1, b1, xs);

  gemm8w<0><<<(MP / 128) * (3 * DIM / 128), 512, 0, stream>>>(
      xs, wqkvT, 3 * DIM, DIM, qkv, nullptr, nullptr, nullptr, nullptr);

  attn_kernel<<<(BATCH * NWIN * HEADS) / 256, 256, 0, stream>>>(qkv, obuf);

  // proj: resf = bf16(x + scatter(attn @ w_proj))
  gemm8w<1><<<(MP / 128) * (DIM / 128), 512, 0, stream>>>(
      obuf, wprojT, DIM, DIM, resf, nullptr, x, nullptr, nullptr);

  lnb_kernel<<<M2 / 4, 256, 0, stream>>>(resf, g2, b2, ln2o);

  gemm8w<2><<<(M2 / 128) * (2 * DIM / 128), 512, 0, stream>>>(
      ln2o, wm1T, 2 * DIM, DIM, h1, nullptr, nullptr, nullptr, b_mlp1);

  // mlp2: out(fp32) = resf + h1 @ w_mlp2 + b
  gemm8w<3><<<(M2 / 128) * (DIM / 128), 512, 0, stream>>>(
      h1, wm2T, DIM, 2 * DIM, nullptr, out, nullptr, resf, b_mlp2);
}

// Round 9
// 596.876 us; speedup vs baseline: 2.9418x; 2.9418x over previous
//
#include <hip/hip_runtime.h>

// ---------------- problem constants ----------------
#define BATCH 8
#define TLEN  4096
#define DIM   768
#define TP    4098            // TLEN padded to multiple of WS=3
#define NWIN  1366            // TP/3
#define HEADS 48
#define HD    16
#define MREAL (BATCH*TP)      // 32784 rows in the rolled/padded sequence
#define MP    32896           // MREAL padded to 257*128 (GEMM tile multiple)
#define M2    (BATCH*TLEN)    // 32768 rows for the MLP path

typedef unsigned short u16;
typedef __bf16  bf16x8  __attribute__((ext_vector_type(8)));
typedef short   short8v __attribute__((ext_vector_type(8)));
typedef float   float4v __attribute__((ext_vector_type(4)));
typedef u16     u16x4   __attribute__((ext_vector_type(4)));

static __device__ __forceinline__ float bf2f(u16 u) {
  unsigned int x = ((unsigned int)u) << 16;
  return __builtin_bit_cast(float, x);
}
static __device__ __forceinline__ u16 f2bf(float f) {  // round-nearest-even
  unsigned int x = __builtin_bit_cast(unsigned int, f);
  x += 0x7fffu + ((x >> 16) & 1u);
  return (u16)(x >> 16);
}

static __device__ __forceinline__ float4v mfma_bf16(short8v a, short8v b, float4v c) {
  return __builtin_amdgcn_mfma_f32_16x16x32_bf16(
      __builtin_bit_cast(bf16x8, a), __builtin_bit_cast(bf16x8, b), c, 0, 0, 0);
}

static __device__ __forceinline__ void gload_lds16(const u16* src, u16* ldsdst) {
  __builtin_amdgcn_global_load_lds(
      (const __attribute__((address_space(1))) void*)src,
      (__attribute__((address_space(3))) void*)ldsdst,
      16, 0, 0);
}

// ---------------- merged weight convert+transpose (4 weights, 1 launch) --------
// w[K][N] fp32 -> wt[N][K] bf16 for qkv, proj, mlp1, mlp2.
#define CVT_E0 1769472                 // 768*2304
#define CVT_E1 (CVT_E0 + 589824)      // + 768*768
#define CVT_E2 (CVT_E1 + 1179648)     // + 768*1536
#define CVT_E3 (CVT_E2 + 1179648)     // + 1536*768
__global__ __launch_bounds__(256) void cvt_all(const float* __restrict__ w0,
                                               const float* __restrict__ w1,
                                               const float* __restrict__ w2,
                                               const float* __restrict__ w3,
                                               u16* __restrict__ t0,
                                               u16* __restrict__ t1,
                                               u16* __restrict__ t2,
                                               u16* __restrict__ t3) {
  int idx = blockIdx.x * 256 + threadIdx.x;
  const float* w; u16* wt; int K, N, e;
  if (idx < CVT_E0)      { w = w0; wt = t0; K = 768;  N = 2304; e = idx; }
  else if (idx < CVT_E1) { w = w1; wt = t1; K = 768;  N = 768;  e = idx - CVT_E0; }
  else if (idx < CVT_E2) { w = w2; wt = t2; K = 768;  N = 1536; e = idx - CVT_E1; }
  else if (idx < CVT_E3) { w = w3; wt = t3; K = 1536; N = 768;  e = idx - CVT_E2; }
  else return;
  int k = e / N, n = e - k * N;
  wt[(size_t)n * K + k] = f2bf(w[e]);
}

// ---------------- LayerNorm fp32-in (wave per row). ROLL: xs = roll(pad(LN(x)),-1) ----
template<bool ROLL>
__global__ __launch_bounds__(256) void ln_kernel(const float* __restrict__ x,
                                                 const float* __restrict__ g,
                                                 const float* __restrict__ bet,
                                                 u16* __restrict__ out) {
  int wave = threadIdx.x >> 6, lane = threadIdx.x & 63;
  int row = blockIdx.x * 4 + wave;
  u16* orow = out + (size_t)row * DIM;

  const float* src;
  if (ROLL) {
    bool zero = (row >= MREAL);
    int t = 0, b = 0;
    if (!zero) {
      b = row / TP;
      int m = row - b * TP;
      t = m + 1; if (t == TP) t = 0;      // xs[m] = xp[(m+1) % TP]
      if (t >= TLEN) zero = true;         // xp pad rows are exact zeros
    }
    if (zero) {
      u16x4 z = {};
#pragma unroll
      for (int c = 0; c < 3; ++c) *(u16x4*)&orow[c * 256 + lane * 4] = z;
      return;
    }
    src = x + ((size_t)b * TLEN + t) * DIM;
  } else {
    src = x + (size_t)row * DIM;
  }

  float v[12];
  float s = 0.f, s2 = 0.f;
#pragma unroll
  for (int c = 0; c < 3; ++c) {
    float4v f = *(const float4v*)&src[c * 256 + lane * 4];
#pragma unroll
    for (int q = 0; q < 4; ++q) { v[c * 4 + q] = f[q]; s += f[q]; s2 += f[q] * f[q]; }
  }
#pragma unroll
  for (int off = 1; off < 64; off <<= 1) {
    s  += __shfl_xor(s, off);
    s2 += __shfl_xor(s2, off);
  }
  float mean = s * (1.f / DIM);
  float var  = s2 * (1.f / DIM) - mean * mean;
  float rs   = rsqrtf(var + 1e-5f);
#pragma unroll
  for (int c = 0; c < 3; ++c) {
    int col = c * 256 + lane * 4;
    float4v gv = *(const float4v*)&g[col];
    float4v bv = *(const float4v*)&bet[col];
    u16x4 o4;
#pragma unroll
    for (int q = 0; q < 4; ++q) o4[q] = f2bf((v[c * 4 + q] - mean) * rs * gv[q] + bv[q]);
    *(u16x4*)&orow[col] = o4;
  }
}

// ---------------- LayerNorm bf16-in (wave per row), rows = M2 ----------------
__global__ __launch_bounds__(256) void lnb_kernel(const u16* __restrict__ xin,
                                                  const float* __restrict__ g,
                                                  const float* __restrict__ bet,
                                                  u16* __restrict__ out) {
  int wave = threadIdx.x >> 6, lane = threadIdx.x & 63;
  int row = blockIdx.x * 4 + wave;
  const u16* src = xin + (size_t)row * DIM;
  u16* orow = out + (size_t)row * DIM;

  float v[12];
  float s = 0.f, s2 = 0.f;
#pragma unroll
  for (int c = 0; c < 3; ++c) {
    u16x4 h = *(const u16x4*)&src[c * 256 + lane * 4];
#pragma unroll
    for (int q = 0; q < 4; ++q) {
      float f = bf2f(h[q]);
      v[c * 4 + q] = f; s += f; s2 += f * f;
    }
  }
#pragma unroll
  for (int off = 1; off < 64; off <<= 1) {
    s  += __shfl_xor(s, off);
    s2 += __shfl_xor(s2, off);
  }
  float mean = s * (1.f / DIM);
  float var  = s2 * (1.f / DIM) - mean * mean;
  float rs   = rsqrtf(var + 1e-5f);
#pragma unroll
  for (int c = 0; c < 3; ++c) {
    int col = c * 256 + lane * 4;
    float4v gv = *(const float4v*)&g[col];
    float4v bv = *(const float4v*)&bet[col];
    u16x4 o4;
#pragma unroll
    for (int q = 0; q < 4; ++q) o4[q] = f2bf((v[c * 4 + q] - mean) * rs * gv[q] + bv[q]);
    *(u16x4*)&orow[col] = o4;
  }
}

// ---------------- window attention: one thread per (window, head) ----------------
__global__ __launch_bounds__(256) void attn_kernel(const u16* __restrict__ qkv,
                                                   u16* __restrict__ o) {
  int gid = blockIdx.x * 256 + threadIdx.x;   // grid sized exactly
  int h = gid % HEADS;
  int w = gid / HEADS;
  int b = w / NWIN, wl = w - b * NWIN;
  size_t row0 = (size_t)b * TP + (size_t)wl * 3;

  float q[3][HD], k[3][HD];
#pragma unroll
  for (int t = 0; t < 3; ++t) {
    const u16* rp = qkv + (row0 + t) * (3 * DIM) + h * HD;
    short8v q0 = *(const short8v*)(rp);
    short8v q1 = *(const short8v*)(rp + 8);
    short8v k0 = *(const short8v*)(rp + DIM);
    short8v k1 = *(const short8v*)(rp + DIM + 8);
#pragma unroll
    for (int d = 0; d < 8; ++d) {
      q[t][d] = bf2f((u16)q0[d]); q[t][d + 8] = bf2f((u16)q1[d]);
      k[t][d] = bf2f((u16)k0[d]); k[t][d + 8] = bf2f((u16)k1[d]);
    }
  }
  float p[3][3];
#pragma unroll
  for (int i = 0; i < 3; ++i)
#pragma unroll
    for (int j = 0; j < 3; ++j) {
      float s = 0.f;
#pragma unroll
      for (int d = 0; d < HD; ++d) s += q[i][d] * k[j][d];
      p[i][j] = s * 0.25f;                 // HD^-0.5
    }
#pragma unroll
  for (int i = 0; i < 3; ++i) {
    float mx = fmaxf(p[i][0], fmaxf(p[i][1], p[i][2]));
    float e0 = __expf(p[i][0] - mx), e1 = __expf(p[i][1] - mx), e2 = __expf(p[i][2] - mx);
    float inv = 1.f / (e0 + e1 + e2);
    p[i][0] = e0 * inv; p[i][1] = e1 * inv; p[i][2] = e2 * inv;
  }
  float acc[3][HD];
#pragma unroll
  for (int i = 0; i < 3; ++i)
#pragma unroll
    for (int d = 0; d < HD; ++d) acc[i][d] = 0.f;
#pragma unroll
  for (int t = 0; t < 3; ++t) {
    const u16* rp = qkv + (row0 + t) * (3 * DIM) + 2 * DIM + h * HD;
    short8v v0 = *(const short8v*)(rp);
    short8v v1 = *(const short8v*)(rp + 8);
#pragma unroll
    for (int d = 0; d < 8; ++d) {
      float a = bf2f((u16)v0[d]), bb = bf2f((u16)v1[d]);
#pragma unroll
      for (int i = 0; i < 3; ++i) { acc[i][d] += p[i][t] * a; acc[i][d + 8] += p[i][t] * bb; }
    }
  }
#pragma unroll
  for (int i = 0; i < 3; ++i) {
    u16 tmp[HD];
#pragma unroll
    for (int d = 0; d < HD; ++d) tmp[d] = f2bf(acc[i][d]);
    u16* op = o + (row0 + i) * DIM + h * HD;
    *(short8v*)op = *(short8v*)tmp;
    *(short8v*)(op + 8) = *(short8v*)(tmp + 8);
  }
}

// ---------------- 128x128 MFMA GEMM, 8 waves, BK=32, 3-stage ring + 1 barrier ---
// A[M][K] bf16, Bt[N][K] bf16. 512 threads (2M x 4N waves, wave tile 64x32).
// LDS = 3 ring bufs x (A 8KB + B 8KB) = 48 KiB -> 3 blocks/CU (r4 residency).
// Live set = 6 frags (24 VGPR) + acc (32 AGPR) -> fits (512,6) cap 85 (r4-proven;
// r6/r8 spilled because they held 12 frags).
// Step t: vmcnt(2) [tile t landed; t+1's 2 loads stay in flight] + lgkmcnt(0)
// [my reads of tile t-1 done] -> ONE s_barrier -> issue stage(t+2) into ring buf
// (t+2)%3 == (t-1)%3 (freed by the barrier) -> 6 ds_read -> 8 MFMA.
// Stage-issue -> vmcnt-wait distance = 2 steps (~800cy) ~ HBM latency: near-zero
// exposed latency vs r4's full vmcnt(0) drain every step. Barrier count unchanged.
// 64B-row swizzle (r7-verified): byte ^= ((row>>1)&3)<<4, both-sides.
// EPI 0: C bf16 plain
// EPI 1: resf bf16 = x + scatter(roll)   (outb=resf, residf=x)
// EPI 2: bias+ReLU bf16
// EPI 3: out fp32 = resf + acc + bias    (outf=out, residb=resf)
template<int EPI>
__global__ __launch_bounds__(512, 6) void gemm8w(const u16* __restrict__ A,
                                                 const u16* __restrict__ Bt,
                                                 int N, int K,
                                                 u16* __restrict__ outb,
                                                 float* __restrict__ outf,
                                                 const float* __restrict__ residf,
                                                 const u16* __restrict__ residb,
                                                 const float* __restrict__ bias) {
  __shared__ u16 As[3][128 * 32];
  __shared__ u16 Bs[3][128 * 32];
  const int tid = threadIdx.x;
  const int wave = tid >> 6, lane = tid & 63;
  const int wm = wave >> 2, wn = wave & 3;          // 2 M-waves x 4 N-waves
  const int r = lane & 15, gq = lane >> 4;

  // bijective XCD chunk swizzle (m204) on linearized bid (x fastest)
  const int nwg = gridDim.x, gx = N >> 7;
  int wg = blockIdx.x;
  int qd = nwg >> 3, rr = nwg & 7, xcd = wg & 7, lid = wg >> 3;
  int swz = (xcd < rr ? xcd * (qd + 1) : rr * (qd + 1) + (xcd - rr) * qd) + lid;
  const int tm = swz / gx, tn = swz - tm * gx;
  const int arow0 = tm * 128, brow0 = tn * 128;

  // staging precompute: tile = 128 rows x 64B; dest byte d = tid*16 (linear),
  // source column pre-swizzled with the same XOR (r7-verified).
  const int srowS = tid >> 2;                                   // d >> 6
  const int scolS = ((((tid & 3) << 4) ^ (((srowS >> 1) & 3) << 4)) >> 1);

  // fragment-read swizzled K-offset (elements); (row>>1)&3 == (r>>1)&3 since
  // row bases are multiples of 16.
  const int kxS = (((gq << 4) ^ (((r >> 1) & 3) << 4)) >> 1);
  const int rA = wm * 64 + r, rB = wn * 32 + r;

  float4v acc[4][2];
#pragma unroll
  for (int i = 0; i < 4; ++i)
#pragma unroll
    for (int j = 0; j < 2; ++j) acc[i][j] = (float4v){0.f, 0.f, 0.f, 0.f};

  auto stage = [&](int buf, int tk) {   // 2 global_load_lds per thread
    gload_lds16(A  + (size_t)(arow0 + srowS) * K + tk * 32 + scolS,
                &As[buf][0] + tid * 8);
    gload_lds16(Bt + (size_t)(brow0 + srowS) * K + tk * 32 + scolS,
                &Bs[buf][0] + tid * 8);
  };

  const int NT = K >> 5;   // 24 for K=768, 48 for K=1536
  stage(0, 0);
  if (NT > 1) stage(1, 1);

  int buf = 0;
  for (int t = 0; t < NT; ++t) {
    if (t + 1 < NT) {
      asm volatile("s_waitcnt vmcnt(2)" ::: "memory");   // tile t landed
    } else {
      asm volatile("s_waitcnt vmcnt(0)" ::: "memory");
    }
    asm volatile("s_waitcnt lgkmcnt(0)" ::: "memory");   // my tile t-1 reads done
    __builtin_amdgcn_sched_barrier(0);
    __builtin_amdgcn_s_barrier();     // joint: tile t visible, buf (t-1)%3 free
    __builtin_amdgcn_sched_barrier(0);

    if (t + 2 < NT) stage((t + 2) % 3, t + 2);   // into freed ring slot

    short8v af[4], bfr[2];
#pragma unroll
    for (int i = 0; i < 4; ++i)
      af[i] = *(const short8v*)&As[buf][(rA + i * 16) * 32 + kxS];
#pragma unroll
    for (int j = 0; j < 2; ++j)
      bfr[j] = *(const short8v*)&Bs[buf][(rB + j * 16) * 32 + kxS];

    __builtin_amdgcn_s_setprio(1);
#pragma unroll
    for (int i = 0; i < 4; ++i)
#pragma unroll
      for (int j = 0; j < 2; ++j)
        acc[i][j] = mfma_bf16(af[i], bfr[j], acc[i][j]);
    __builtin_amdgcn_s_setprio(0);

    buf = (buf + 1 == 3) ? 0 : buf + 1;
  }

  // epilogue: D mapping col=lane&15, row=(lane>>4)*4+reg  [m89-verified]
#pragma unroll
  for (int i = 0; i < 4; ++i) {
#pragma unroll
    for (int j = 0; j < 2; ++j) {
      int colg = brow0 + wn * 32 + j * 16 + r;
      int rowb = arow0 + wm * 64 + i * 16 + gq * 4;
#pragma unroll
      for (int v = 0; v < 4; ++v) {
        int rg = rowb + v;
        float val = acc[i][j][v];
        if constexpr (EPI == 0) {
          outb[(size_t)rg * N + colg] = f2bf(val);
        } else if constexpr (EPI == 1) {
          if (rg < MREAL) {
            int b = rg / TP, m = rg - b * TP;
            int t = m + 1; if (t == TP) t = 0;
            if (t < TLEN) {
              size_t idx = ((size_t)b * TLEN + t) * DIM + colg;
              outb[idx] = f2bf(residf[idx] + val);
            }
          }
        } else if constexpr (EPI == 2) {
          float z = val + bias[colg];
          outb[(size_t)rg * N + colg] = f2bf(z > 0.f ? z : 0.f);
        } else {
          size_t idx = (size_t)rg * N + colg;
          outf[idx] = bf2f(residb[idx]) + val + bias[colg];
        }
      }
    }
  }
}

// ---------------- host ----------------
extern "C" void kernel_launch(void* const* d_in, const int* in_sizes, int n_in,
                              void* d_out, int out_size, void* d_ws, size_t ws_size,
                              hipStream_t stream) {
  const float* x      = (const float*)d_in[0];
  const float* g1     = (const float*)d_in[1];
  const float* b1     = (const float*)d_in[2];
  const float* w_qkv  = (const float*)d_in[3];
  const float* w_proj = (const float*)d_in[4];
  const float* g2     = (const float*)d_in[5];
  const float* b2     = (const float*)d_in[6];
  const float* w_mlp1 = (const float*)d_in[7];
  const float* b_mlp1 = (const float*)d_in[8];
  const float* w_mlp2 = (const float*)d_in[9];
  const float* b_mlp2 = (const float*)d_in[10];
  float* out = (float*)d_out;

  // workspace layout (~262 MB total)
  u16* xs     = (u16*)d_ws;                        // MP*768 bf16 (LN1, rolled/padded)
  u16* qkv    = xs     + (size_t)MP * DIM;         // MP*2304 bf16
  u16* obuf   = qkv    + (size_t)MP * 3 * DIM;     // MP*768 bf16 (attn out)
  u16* wqkvT  = obuf   + (size_t)MP * DIM;         // [2304][768]
  u16* wprojT = wqkvT  + (size_t)3 * DIM * DIM;    // [768][768]
  u16* wm1T   = wprojT + (size_t)DIM * DIM;        // [1536][768]
  u16* wm2T   = wm1T   + (size_t)2 * DIM * DIM;    // [768][1536]
  // region reuse across the pipeline (each producer runs after the consumer
  // of the previous tenant):
  u16* resf = xs;    // M2*768  bf16 residual trunk (xs dead after QKV GEMM)
  u16* ln2o = obuf;  // M2*768  (obuf dead after proj GEMM)
  u16* h1   = qkv;   // M2*1536 (qkv dead after attn)

  cvt_all<<<(CVT_E3 + 255) / 256, 256, 0, stream>>>(
      w_qkv, w_proj, w_mlp1, w_mlp2, wqkvT, wprojT, wm1T, wm2T);

  ln_kernel<true><<<MP / 4, 256, 0, stream>>>(x, g1, b1, xs);

  gemm8w<0><<<(MP / 128) * (3 * DIM / 128), 512, 0, stream>>>(
      xs, wqkvT, 3 * DIM, DIM, qkv, nullptr, nullptr, nullptr, nullptr);

  attn_kernel<<<(BATCH * NWIN * HEADS) / 256, 256, 0, stream>>>(qkv, obuf);

  // proj: resf = bf16(x + scatter(attn @ w_proj))
  gemm8w<1><<<(MP / 128) * (DIM / 128), 512, 0, stream>>>(
      obuf, wprojT, DIM, DIM, resf, nullptr, x, nullptr, nullptr);

  lnb_kernel<<<M2 / 4, 256, 0, stream>>>(resf, g2, b2, ln2o);

  gemm8w<2><<<(M2 / 128) * (2 * DIM / 128), 512, 0, stream>>>(
      ln2o, wm1T, 2 * DIM, DIM, h1, nullptr, nullptr, nullptr, b_mlp1);

  // mlp2: out(fp32) = resf + h1 @ w_mlp2 + b
  gemm8w<3><<<(M2 / 128) * (DIM / 128), 512, 0, stream>>>(
      h1, wm2T, DIM, 2 * DIM, nullptr, out, nullptr, resf, b_mlp2);
}

// Round 10
// 550.763 us; speedup vs baseline: 3.1881x; 1.0837x over previous
//
#include <hip/hip_runtime.h>

// ---------------- problem constants ----------------
#define BATCH 8
#define TLEN  4096
#define DIM   768
#define TP    4098            // TLEN padded to multiple of WS=3
#define NWIN  1366            // TP/3
#define HEADS 48
#define HD    16
#define MREAL (BATCH*TP)      // 32784 rows in the rolled/padded sequence
#define MP    32896           // MREAL padded to 257*128 (GEMM tile multiple)
#define M2    (BATCH*TLEN)    // 32768 rows for the MLP path

typedef unsigned short u16;
typedef __bf16  bf16x8  __attribute__((ext_vector_type(8)));
typedef short   short8v __attribute__((ext_vector_type(8)));
typedef float   float4v __attribute__((ext_vector_type(4)));
typedef u16     u16x4   __attribute__((ext_vector_type(4)));

static __device__ __forceinline__ float bf2f(u16 u) {
  unsigned int x = ((unsigned int)u) << 16;
  return __builtin_bit_cast(float, x);
}
static __device__ __forceinline__ u16 f2bf(float f) {  // round-nearest-even
  unsigned int x = __builtin_bit_cast(unsigned int, f);
  x += 0x7fffu + ((x >> 16) & 1u);
  return (u16)(x >> 16);
}

static __device__ __forceinline__ float4v mfma_bf16(short8v a, short8v b, float4v c) {
  return __builtin_amdgcn_mfma_f32_16x16x32_bf16(
      __builtin_bit_cast(bf16x8, a), __builtin_bit_cast(bf16x8, b), c, 0, 0, 0);
}

static __device__ __forceinline__ void gload_lds16(const u16* src, u16* ldsdst) {
  __builtin_amdgcn_global_load_lds(
      (const __attribute__((address_space(1))) void*)src,
      (__attribute__((address_space(3))) void*)ldsdst,
      16, 0, 0);
}

// ---------------- merged weight convert+transpose (4 weights, 1 launch) --------
// w[K][N] fp32 -> wt[N][K] bf16 for qkv, proj, mlp1, mlp2.
#define CVT_E0 1769472                 // 768*2304
#define CVT_E1 (CVT_E0 + 589824)      // + 768*768
#define CVT_E2 (CVT_E1 + 1179648)     // + 768*1536
#define CVT_E3 (CVT_E2 + 1179648)     // + 1536*768
__global__ __launch_bounds__(256) void cvt_all(const float* __restrict__ w0,
                                               const float* __restrict__ w1,
                                               const float* __restrict__ w2,
                                               const float* __restrict__ w3,
                                               u16* __restrict__ t0,
                                               u16* __restrict__ t1,
                                               u16* __restrict__ t2,
                                               u16* __restrict__ t3) {
  int idx = blockIdx.x * 256 + threadIdx.x;
  const float* w; u16* wt; int K, N, e;
  if (idx < CVT_E0)      { w = w0; wt = t0; K = 768;  N = 2304; e = idx; }
  else if (idx < CVT_E1) { w = w1; wt = t1; K = 768;  N = 768;  e = idx - CVT_E0; }
  else if (idx < CVT_E2) { w = w2; wt = t2; K = 768;  N = 1536; e = idx - CVT_E1; }
  else if (idx < CVT_E3) { w = w3; wt = t3; K = 1536; N = 768;  e = idx - CVT_E2; }
  else return;
  int k = e / N, n = e - k * N;
  wt[(size_t)n * K + k] = f2bf(w[e]);
}

// ---------------- LayerNorm fp32-in (wave per row). ROLL: xs = roll(pad(LN(x)),-1) ----
template<bool ROLL>
__global__ __launch_bounds__(256) void ln_kernel(const float* __restrict__ x,
                                                 const float* __restrict__ g,
                                                 const float* __restrict__ bet,
                                                 u16* __restrict__ out) {
  int wave = threadIdx.x >> 6, lane = threadIdx.x & 63;
  int row = blockIdx.x * 4 + wave;
  u16* orow = out + (size_t)row * DIM;

  const float* src;
  if (ROLL) {
    bool zero = (row >= MREAL);
    int t = 0, b = 0;
    if (!zero) {
      b = row / TP;
      int m = row - b * TP;
      t = m + 1; if (t == TP) t = 0;      // xs[m] = xp[(m+1) % TP]
      if (t >= TLEN) zero = true;         // xp pad rows are exact zeros
    }
    if (zero) {
      u16x4 z = {};
#pragma unroll
      for (int c = 0; c < 3; ++c) *(u16x4*)&orow[c * 256 + lane * 4] = z;
      return;
    }
    src = x + ((size_t)b * TLEN + t) * DIM;
  } else {
    src = x + (size_t)row * DIM;
  }

  float v[12];
  float s = 0.f, s2 = 0.f;
#pragma unroll
  for (int c = 0; c < 3; ++c) {
    float4v f = *(const float4v*)&src[c * 256 + lane * 4];
#pragma unroll
    for (int q = 0; q < 4; ++q) { v[c * 4 + q] = f[q]; s += f[q]; s2 += f[q] * f[q]; }
  }
#pragma unroll
  for (int off = 1; off < 64; off <<= 1) {
    s  += __shfl_xor(s, off);
    s2 += __shfl_xor(s2, off);
  }
  float mean = s * (1.f / DIM);
  float var  = s2 * (1.f / DIM) - mean * mean;
  float rs   = rsqrtf(var + 1e-5f);
#pragma unroll
  for (int c = 0; c < 3; ++c) {
    int col = c * 256 + lane * 4;
    float4v gv = *(const float4v*)&g[col];
    float4v bv = *(const float4v*)&bet[col];
    u16x4 o4;
#pragma unroll
    for (int q = 0; q < 4; ++q) o4[q] = f2bf((v[c * 4 + q] - mean) * rs * gv[q] + bv[q]);
    *(u16x4*)&orow[col] = o4;
  }
}

// ---------------- LayerNorm bf16-in (wave per row), rows = M2 ----------------
__global__ __launch_bounds__(256) void lnb_kernel(const u16* __restrict__ xin,
                                                  const float* __restrict__ g,
                                                  const float* __restrict__ bet,
                                                  u16* __restrict__ out) {
  int wave = threadIdx.x >> 6, lane = threadIdx.x & 63;
  int row = blockIdx.x * 4 + wave;
  const u16* src = xin + (size_t)row * DIM;
  u16* orow = out + (size_t)row * DIM;

  float v[12];
  float s = 0.f, s2 = 0.f;
#pragma unroll
  for (int c = 0; c < 3; ++c) {
    u16x4 h = *(const u16x4*)&src[c * 256 + lane * 4];
#pragma unroll
    for (int q = 0; q < 4; ++q) {
      float f = bf2f(h[q]);
      v[c * 4 + q] = f; s += f; s2 += f * f;
    }
  }
#pragma unroll
  for (int off = 1; off < 64; off <<= 1) {
    s  += __shfl_xor(s, off);
    s2 += __shfl_xor(s2, off);
  }
  float mean = s * (1.f / DIM);
  float var  = s2 * (1.f / DIM) - mean * mean;
  float rs   = rsqrtf(var + 1e-5f);
#pragma unroll
  for (int c = 0; c < 3; ++c) {
    int col = c * 256 + lane * 4;
    float4v gv = *(const float4v*)&g[col];
    float4v bv = *(const float4v*)&bet[col];
    u16x4 o4;
#pragma unroll
    for (int q = 0; q < 4; ++q) o4[q] = f2bf((v[c * 4 + q] - mean) * rs * gv[q] + bv[q]);
    *(u16x4*)&orow[col] = o4;
  }
}

// ---------------- window attention: one thread per (window, head) ----------------
__global__ __launch_bounds__(256) void attn_kernel(const u16* __restrict__ qkv,
                                                   u16* __restrict__ o) {
  int gid = blockIdx.x * 256 + threadIdx.x;   // grid sized exactly
  int h = gid % HEADS;
  int w = gid / HEADS;
  int b = w / NWIN, wl = w - b * NWIN;
  size_t row0 = (size_t)b * TP + (size_t)wl * 3;

  float q[3][HD], k[3][HD];
#pragma unroll
  for (int t = 0; t < 3; ++t) {
    const u16* rp = qkv + (row0 + t) * (3 * DIM) + h * HD;
    short8v q0 = *(const short8v*)(rp);
    short8v q1 = *(const short8v*)(rp + 8);
    short8v k0 = *(const short8v*)(rp + DIM);
    short8v k1 = *(const short8v*)(rp + DIM + 8);
#pragma unroll
    for (int d = 0; d < 8; ++d) {
      q[t][d] = bf2f((u16)q0[d]); q[t][d + 8] = bf2f((u16)q1[d]);
      k[t][d] = bf2f((u16)k0[d]); k[t][d + 8] = bf2f((u16)k1[d]);
    }
  }
  float p[3][3];
#pragma unroll
  for (int i = 0; i < 3; ++i)
#pragma unroll
    for (int j = 0; j < 3; ++j) {
      float s = 0.f;
#pragma unroll
      for (int d = 0; d < HD; ++d) s += q[i][d] * k[j][d];
      p[i][j] = s * 0.25f;                 // HD^-0.5
    }
#pragma unroll
  for (int i = 0; i < 3; ++i) {
    float mx = fmaxf(p[i][0], fmaxf(p[i][1], p[i][2]));
    float e0 = __expf(p[i][0] - mx), e1 = __expf(p[i][1] - mx), e2 = __expf(p[i][2] - mx);
    float inv = 1.f / (e0 + e1 + e2);
    p[i][0] = e0 * inv; p[i][1] = e1 * inv; p[i][2] = e2 * inv;
  }
  float acc[3][HD];
#pragma unroll
  for (int i = 0; i < 3; ++i)
#pragma unroll
    for (int d = 0; d < HD; ++d) acc[i][d] = 0.f;
#pragma unroll
  for (int t = 0; t < 3; ++t) {
    const u16* rp = qkv + (row0 + t) * (3 * DIM) + 2 * DIM + h * HD;
    short8v v0 = *(const short8v*)(rp);
    short8v v1 = *(const short8v*)(rp + 8);
#pragma unroll
    for (int d = 0; d < 8; ++d) {
      float a = bf2f((u16)v0[d]), bb = bf2f((u16)v1[d]);
#pragma unroll
      for (int i = 0; i < 3; ++i) { acc[i][d] += p[i][t] * a; acc[i][d + 8] += p[i][t] * bb; }
    }
  }
#pragma unroll
  for (int i = 0; i < 3; ++i) {
    u16 tmp[HD];
#pragma unroll
    for (int d = 0; d < HD; ++d) tmp[d] = f2bf(acc[i][d]);
    u16* op = o + (row0 + i) * DIM + h * HD;
    *(short8v*)op = *(short8v*)tmp;
    *(short8v*)(op + 8) = *(short8v*)(tmp + 8);
  }
}

// ---------------- 128x128 MFMA GEMM, 4 waves (2x2), wave tile 64x64 -------------
// m97-structure: 16 ds_read_b128 -> 32 MFMA per wave-step (2x the MFMA:ds ratio
// of the 64x32 tiling; LDS traffic 64KB/step vs 96KB). A[M][K], Bt[N][K] bf16.
// LDS 32 KiB single buffer; launch_bounds(256,3): VGPR cap 170 fits 16 frags
// (64 VGPR) + acc (64 AGPR) + addr (m98: same structure = 164 VGPR, 3/SIMD),
// 3 blocks/CU. Per K-step: read 16 frags -> lgkmcnt(0)+barrier (buffer dead)
// -> stage(t+1) into SAME buffer (hides under 32 MFMAs + cross-block TLP)
// -> MFMAs -> vmcnt(0)+barrier.
// XOR swizzle byte^=((row&7)<<4) both-sides (r3/r4-verified).
// EPI 0: C bf16 plain
// EPI 1: resf bf16 = x + scatter(roll)   (outb=resf, residf=x)
// EPI 2: bias+ReLU bf16
// EPI 3: out fp32 = resf + acc + bias    (outf=out, residb=resf)
template<int EPI>
__global__ __launch_bounds__(256, 3) void gemm4w(const u16* __restrict__ A,
                                                 const u16* __restrict__ Bt,
                                                 int N, int K,
                                                 u16* __restrict__ outb,
                                                 float* __restrict__ outf,
                                                 const float* __restrict__ residf,
                                                 const u16* __restrict__ residb,
                                                 const float* __restrict__ bias) {
  __shared__ u16 As[128 * 64];
  __shared__ u16 Bs[128 * 64];
  const int tid = threadIdx.x;
  const int wave = tid >> 6, lane = tid & 63;
  const int wm = wave >> 1, wn = wave & 1;          // 2 M-waves x 2 N-waves
  const int r = lane & 15, gq = lane >> 4;

  // bijective XCD chunk swizzle (m204) on linearized bid (x fastest)
  const int nwg = gridDim.x, gx = N >> 7;
  int wg = blockIdx.x;
  int qd = nwg >> 3, rr = nwg & 7, xcd = wg & 7, lid = wg >> 3;
  int swz = (xcd < rr ? xcd * (qd + 1) : rr * (qd + 1) + (xcd - rr) * qd) + lid;
  const int tm = swz / gx, tn = swz - tm * gx;
  const int arow0 = tm * 128, brow0 = tn * 128;

  // staging precompute: 4 chunks of 4 KiB per matrix; linear LDS dest
  // d = c*4096 + tid*16 bytes, global source column pre-swizzled (same XOR).
  int srow[4], scol[4];
#pragma unroll
  for (int c = 0; c < 4; ++c) {
    int d = c * 4096 + tid * 16;
    srow[c] = d >> 7;
    scol[c] = (((d & 127) ^ ((srow[c] & 7) << 4)) >> 1);
  }

  // fragment-read swizzled K-offsets (elements); row&7 == r&7 (bases mult of 16)
  const int kx0 = (((gq * 16) ^ ((r & 7) << 4)) >> 1);        // kk = 0
  const int kx1 = (((64 + gq * 16) ^ ((r & 7) << 4)) >> 1);   // kk = 1
  const int rA = wm * 64 + r, rB = wn * 64 + r;

  float4v acc[4][4];
#pragma unroll
  for (int i = 0; i < 4; ++i)
#pragma unroll
    for (int j = 0; j < 4; ++j) acc[i][j] = (float4v){0.f, 0.f, 0.f, 0.f};

  auto stage = [&](int tk) {   // 8 global_load_lds per thread, same buffer
#pragma unroll
    for (int c = 0; c < 4; ++c) {
      gload_lds16(A  + (size_t)(arow0 + srow[c]) * K + tk * 64 + scol[c],
                  &As[0] + c * 2048 + tid * 8);
      gload_lds16(Bt + (size_t)(brow0 + srow[c]) * K + tk * 64 + scol[c],
                  &Bs[0] + c * 2048 + tid * 8);
    }
  };

  const int NT = K >> 6;
  stage(0);
  asm volatile("s_waitcnt vmcnt(0)" ::: "memory");
  __builtin_amdgcn_sched_barrier(0);
  __builtin_amdgcn_s_barrier();       // tile 0 fully in LDS

  for (int t = 0; t < NT; ++t) {
    short8v af[8], bfr[8];
#pragma unroll
    for (int i = 0; i < 4; ++i) {
      af[2 * i]     = *(const short8v*)&As[(rA + i * 16) * 64 + kx0];
      af[2 * i + 1] = *(const short8v*)&As[(rA + i * 16) * 64 + kx1];
    }
#pragma unroll
    for (int j = 0; j < 4; ++j) {
      bfr[2 * j]     = *(const short8v*)&Bs[(rB + j * 16) * 64 + kx0];
      bfr[2 * j + 1] = *(const short8v*)&Bs[(rB + j * 16) * 64 + kx1];
    }
    asm volatile("s_waitcnt lgkmcnt(0)" ::: "memory");  // my frag reads complete
    __builtin_amdgcn_sched_barrier(0);
    __builtin_amdgcn_s_barrier();       // ALL waves done reading -> buffer dead
    __builtin_amdgcn_sched_barrier(0);

    if (t + 1 < NT) stage(t + 1);       // overwrite same buffer under MFMAs

    __builtin_amdgcn_s_setprio(1);
#pragma unroll
    for (int i = 0; i < 4; ++i)
#pragma unroll
      for (int j = 0; j < 4; ++j) {
        acc[i][j] = mfma_bf16(af[2 * i],     bfr[2 * j],     acc[i][j]);
        acc[i][j] = mfma_bf16(af[2 * i + 1], bfr[2 * j + 1], acc[i][j]);
      }
    __builtin_amdgcn_s_setprio(0);

    if (t + 1 < NT) {
      asm volatile("s_waitcnt vmcnt(0)" ::: "memory");  // my stage loads landed
      __builtin_amdgcn_sched_barrier(0);
      __builtin_amdgcn_s_barrier();     // everyone's stage landed & visible
      __builtin_amdgcn_sched_barrier(0);
    }
  }

  // epilogue: D mapping col=lane&15, row=(lane>>4)*4+reg  [m89-verified]
#pragma unroll
  for (int i = 0; i < 4; ++i) {
#pragma unroll
    for (int j = 0; j < 4; ++j) {
      int colg = brow0 + wn * 64 + j * 16 + r;
      int rowb = arow0 + wm * 64 + i * 16 + gq * 4;
#pragma unroll
      for (int v = 0; v < 4; ++v) {
        int rg = rowb + v;
        float val = acc[i][j][v];
        if constexpr (EPI == 0) {
          outb[(size_t)rg * N + colg] = f2bf(val);
        } else if constexpr (EPI == 1) {
          if (rg < MREAL) {
            int b = rg / TP, m = rg - b * TP;
            int t = m + 1; if (t == TP) t = 0;
            if (t < TLEN) {
              size_t idx = ((size_t)b * TLEN + t) * DIM + colg;
              outb[idx] = f2bf(residf[idx] + val);
            }
          }
        } else if constexpr (EPI == 2) {
          float z = val + bias[colg];
          outb[(size_t)rg * N + colg] = f2bf(z > 0.f ? z : 0.f);
        } else {
          size_t idx = (size_t)rg * N + colg;
          outf[idx] = bf2f(residb[idx]) + val + bias[colg];
        }
      }
    }
  }
}

// ---------------- host ----------------
extern "C" void kernel_launch(void* const* d_in, const int* in_sizes, int n_in,
                              void* d_out, int out_size, void* d_ws, size_t ws_size,
                              hipStream_t stream) {
  const float* x      = (const float*)d_in[0];
  const float* g1     = (const float*)d_in[1];
  const float* b1     = (const float*)d_in[2];
  const float* w_qkv  = (const float*)d_in[3];
  const float* w_proj = (const float*)d_in[4];
  const float* g2     = (const float*)d_in[5];
  const float* b2     = (const float*)d_in[6];
  const float* w_mlp1 = (const float*)d_in[7];
  const float* b_mlp1 = (const float*)d_in[8];
  const float* w_mlp2 = (const float*)d_in[9];
  const float* b_mlp2 = (const float*)d_in[10];
  float* out = (float*)d_out;

  // workspace layout (~262 MB total)
  u16* xs     = (u16*)d_ws;                        // MP*768 bf16 (LN1, rolled/padded)
  u16* qkv    = xs     + (size_t)MP * DIM;         // MP*2304 bf16
  u16* obuf   = qkv    + (size_t)MP * 3 * DIM;     // MP*768 bf16 (attn out)
  u16* wqkvT  = obuf   + (size_t)MP * DIM;         // [2304][768]
  u16* wprojT = wqkvT  + (size_t)3 * DIM * DIM;    // [768][768]
  u16* wm1T   = wprojT + (size_t)DIM * DIM;        // [1536][768]
  u16* wm2T   = wm1T   + (size_t)2 * DIM * DIM;    // [768][1536]
  // region reuse across the pipeline (each producer runs after the consumer
  // of the previous tenant):
  u16* resf = xs;    // M2*768  bf16 residual trunk (xs dead after QKV GEMM)
  u16* ln2o = obuf;  // M2*768  (obuf dead after proj GEMM)
  u16* h1   = qkv;   // M2*1536 (qkv dead after attn)

  cvt_all<<<(CVT_E3 + 255) / 256, 256, 0, stream>>>(
      w_qkv, w_proj, w_mlp1, w_mlp2, wqkvT, wprojT, wm1T, wm2T);

  ln_kernel<true><<<MP / 4, 256, 0, stream>>>(x, g1, b1, xs);

  gemm4w<0><<<(MP / 128) * (3 * DIM / 128), 256, 0, stream>>>(
      xs, wqkvT, 3 * DIM, DIM, qkv, nullptr, nullptr, nullptr, nullptr);

  attn_kernel<<<(BATCH * NWIN * HEADS) / 256, 256, 0, stream>>>(qkv, obuf);

  // proj: resf = bf16(x + scatter(attn @ w_proj))
  gemm4w<1><<<(MP / 128) * (DIM / 128), 256, 0, stream>>>(
      obuf, wprojT, DIM, DIM, resf, nullptr, x, nullptr, nullptr);

  lnb_kernel<<<M2 / 4, 256, 0, stream>>>(resf, g2, b2, ln2o);

  gemm4w<2><<<(M2 / 128) * (2 * DIM / 128), 256, 0, stream>>>(
      ln2o, wm1T, 2 * DIM, DIM, h1, nullptr, nullptr, nullptr, b_mlp1);

  // mlp2: out(fp32) = resf + h1 @ w_mlp2 + b
  gemm4w<3><<<(M2 / 128) * (DIM / 128), 256, 0, stream>>>(
      h1, wm2T, DIM, 2 * DIM, nullptr, out, nullptr, resf, b_mlp2);
}

// Round 11
// 518.589 us; speedup vs baseline: 3.3859x; 1.0620x over previous
//
#include <hip/hip_runtime.h>

// ---------------- problem constants ----------------
#define BATCH 8
#define TLEN  4096
#define DIM   768
#define TP    4098            // TLEN padded to multiple of WS=3
#define NWIN  1366            // TP/3
#define HEADS 48
#define HD    16
#define MREAL (BATCH*TP)      // 32784 rows in the rolled/padded sequence
#define MP    32896           // MREAL padded to 257*128 (GEMM tile multiple)
#define M2    (BATCH*TLEN)    // 32768 rows for the MLP path

typedef unsigned short u16;
typedef __bf16  bf16x8  __attribute__((ext_vector_type(8)));
typedef short   short8v __attribute__((ext_vector_type(8)));
typedef float   float4v __attribute__((ext_vector_type(4)));
typedef u16     u16x4   __attribute__((ext_vector_type(4)));

static __device__ __forceinline__ float bf2f(u16 u) {
  unsigned int x = ((unsigned int)u) << 16;
  return __builtin_bit_cast(float, x);
}
static __device__ __forceinline__ u16 f2bf(float f) {  // round-nearest-even
  unsigned int x = __builtin_bit_cast(unsigned int, f);
  x += 0x7fffu + ((x >> 16) & 1u);
  return (u16)(x >> 16);
}

static __device__ __forceinline__ float4v mfma_bf16(short8v a, short8v b, float4v c) {
  return __builtin_amdgcn_mfma_f32_16x16x32_bf16(
      __builtin_bit_cast(bf16x8, a), __builtin_bit_cast(bf16x8, b), c, 0, 0, 0);
}

static __device__ __forceinline__ void gload_lds16(const u16* src, u16* ldsdst) {
  __builtin_amdgcn_global_load_lds(
      (const __attribute__((address_space(1))) void*)src,
      (__attribute__((address_space(3))) void*)ldsdst,
      16, 0, 0);
}

// ---------------- prep: LN1(+roll/pad) AND all 4 weight transposes, ONE launch --
// blocks [0, MP/4)            : LN1 rows (4 rows/block, wave per row)
// blocks [MP/4, MP/4 + NCVT)  : weight cvt+transpose w[K][N] fp32 -> wt[N][K] bf16
#define LN_BLOCKS (MP / 4)
#define CVT_E0 1769472                // 768*2304
#define CVT_E1 (CVT_E0 + 589824)     // + 768*768
#define CVT_E2 (CVT_E1 + 1179648)    // + 768*1536
#define CVT_E3 (CVT_E2 + 1179648)    // + 1536*768
#define NCVT ((CVT_E3 + 255) / 256)
__global__ __launch_bounds__(256) void prep_kernel(
    const float* __restrict__ x, const float* __restrict__ g,
    const float* __restrict__ bet, u16* __restrict__ out,
    const float* __restrict__ w0, const float* __restrict__ w1,
    const float* __restrict__ w2, const float* __restrict__ w3,
    u16* __restrict__ t0, u16* __restrict__ t1,
    u16* __restrict__ t2, u16* __restrict__ t3) {
  if (blockIdx.x >= LN_BLOCKS) {
    int idx = (blockIdx.x - LN_BLOCKS) * 256 + threadIdx.x;
    const float* w; u16* wt; int K, N, e;
    if (idx < CVT_E0)      { w = w0; wt = t0; K = 768;  N = 2304; e = idx; }
    else if (idx < CVT_E1) { w = w1; wt = t1; K = 768;  N = 768;  e = idx - CVT_E0; }
    else if (idx < CVT_E2) { w = w2; wt = t2; K = 768;  N = 1536; e = idx - CVT_E1; }
    else if (idx < CVT_E3) { w = w3; wt = t3; K = 1536; N = 768;  e = idx - CVT_E2; }
    else return;
    int k = e / N, n = e - k * N;
    wt[(size_t)n * K + k] = f2bf(w[e]);
    return;
  }
  int wave = threadIdx.x >> 6, lane = threadIdx.x & 63;
  int row = blockIdx.x * 4 + wave;
  u16* orow = out + (size_t)row * DIM;

  bool zero = (row >= MREAL);
  int t = 0, b = 0;
  if (!zero) {
    b = row / TP;
    int m = row - b * TP;
    t = m + 1; if (t == TP) t = 0;      // xs[m] = xp[(m+1) % TP]
    if (t >= TLEN) zero = true;         // xp pad rows are exact zeros
  }
  if (zero) {
    u16x4 z = {};
#pragma unroll
    for (int c = 0; c < 3; ++c) *(u16x4*)&orow[c * 256 + lane * 4] = z;
    return;
  }
  const float* src = x + ((size_t)b * TLEN + t) * DIM;

  float v[12];
  float s = 0.f, s2 = 0.f;
#pragma unroll
  for (int c = 0; c < 3; ++c) {
    float4v f = *(const float4v*)&src[c * 256 + lane * 4];
#pragma unroll
    for (int q = 0; q < 4; ++q) { v[c * 4 + q] = f[q]; s += f[q]; s2 += f[q] * f[q]; }
  }
#pragma unroll
  for (int off = 1; off < 64; off <<= 1) {
    s  += __shfl_xor(s, off);
    s2 += __shfl_xor(s2, off);
  }
  float mean = s * (1.f / DIM);
  float var  = s2 * (1.f / DIM) - mean * mean;
  float rs   = rsqrtf(var + 1e-5f);
#pragma unroll
  for (int c = 0; c < 3; ++c) {
    int col = c * 256 + lane * 4;
    float4v gv = *(const float4v*)&g[col];
    float4v bv = *(const float4v*)&bet[col];
    u16x4 o4;
#pragma unroll
    for (int q = 0; q < 4; ++q) o4[q] = f2bf((v[c * 4 + q] - mean) * rs * gv[q] + bv[q]);
    *(u16x4*)&orow[col] = o4;
  }
}

// ---------------- LayerNorm bf16-in (wave per row), rows = M2 ----------------
__global__ __launch_bounds__(256) void lnb_kernel(const u16* __restrict__ xin,
                                                  const float* __restrict__ g,
                                                  const float* __restrict__ bet,
                                                  u16* __restrict__ out) {
  int wave = threadIdx.x >> 6, lane = threadIdx.x & 63;
  int row = blockIdx.x * 4 + wave;
  const u16* src = xin + (size_t)row * DIM;
  u16* orow = out + (size_t)row * DIM;

  float v[12];
  float s = 0.f, s2 = 0.f;
#pragma unroll
  for (int c = 0; c < 3; ++c) {
    u16x4 h = *(const u16x4*)&src[c * 256 + lane * 4];
#pragma unroll
    for (int q = 0; q < 4; ++q) {
      float f = bf2f(h[q]);
      v[c * 4 + q] = f; s += f; s2 += f * f;
    }
  }
#pragma unroll
  for (int off = 1; off < 64; off <<= 1) {
    s  += __shfl_xor(s, off);
    s2 += __shfl_xor(s2, off);
  }
  float mean = s * (1.f / DIM);
  float var  = s2 * (1.f / DIM) - mean * mean;
  float rs   = rsqrtf(var + 1e-5f);
#pragma unroll
  for (int c = 0; c < 3; ++c) {
    int col = c * 256 + lane * 4;
    float4v gv = *(const float4v*)&g[col];
    float4v bv = *(const float4v*)&bet[col];
    u16x4 o4;
#pragma unroll
    for (int q = 0; q < 4; ++q) o4[q] = f2bf((v[c * 4 + q] - mean) * rs * gv[q] + bv[q]);
    *(u16x4*)&orow[col] = o4;
  }
}

// ---------------- window attention: one thread per (window, head) ----------------
__global__ __launch_bounds__(256) void attn_kernel(const u16* __restrict__ qkv,
                                                   u16* __restrict__ o) {
  int gid = blockIdx.x * 256 + threadIdx.x;   // grid sized exactly
  int h = gid % HEADS;
  int w = gid / HEADS;
  int b = w / NWIN, wl = w - b * NWIN;
  size_t row0 = (size_t)b * TP + (size_t)wl * 3;

  float q[3][HD], k[3][HD];
#pragma unroll
  for (int t = 0; t < 3; ++t) {
    const u16* rp = qkv + (row0 + t) * (3 * DIM) + h * HD;
    short8v q0 = *(const short8v*)(rp);
    short8v q1 = *(const short8v*)(rp + 8);
    short8v k0 = *(const short8v*)(rp + DIM);
    short8v k1 = *(const short8v*)(rp + DIM + 8);
#pragma unroll
    for (int d = 0; d < 8; ++d) {
      q[t][d] = bf2f((u16)q0[d]); q[t][d + 8] = bf2f((u16)q1[d]);
      k[t][d] = bf2f((u16)k0[d]); k[t][d + 8] = bf2f((u16)k1[d]);
    }
  }
  float p[3][3];
#pragma unroll
  for (int i = 0; i < 3; ++i)
#pragma unroll
    for (int j = 0; j < 3; ++j) {
      float s = 0.f;
#pragma unroll
      for (int d = 0; d < HD; ++d) s += q[i][d] * k[j][d];
      p[i][j] = s * 0.25f;                 // HD^-0.5
    }
#pragma unroll
  for (int i = 0; i < 3; ++i) {
    float mx = fmaxf(p[i][0], fmaxf(p[i][1], p[i][2]));
    float e0 = __expf(p[i][0] - mx), e1 = __expf(p[i][1] - mx), e2 = __expf(p[i][2] - mx);
    float inv = 1.f / (e0 + e1 + e2);
    p[i][0] = e0 * inv; p[i][1] = e1 * inv; p[i][2] = e2 * inv;
  }
  float acc[3][HD];
#pragma unroll
  for (int i = 0; i < 3; ++i)
#pragma unroll
    for (int d = 0; d < HD; ++d) acc[i][d] = 0.f;
#pragma unroll
  for (int t = 0; t < 3; ++t) {
    const u16* rp = qkv + (row0 + t) * (3 * DIM) + 2 * DIM + h * HD;
    short8v v0 = *(const short8v*)(rp);
    short8v v1 = *(const short8v*)(rp + 8);
#pragma unroll
    for (int d = 0; d < 8; ++d) {
      float a = bf2f((u16)v0[d]), bb = bf2f((u16)v1[d]);
#pragma unroll
      for (int i = 0; i < 3; ++i) { acc[i][d] += p[i][t] * a; acc[i][d + 8] += p[i][t] * bb; }
    }
  }
#pragma unroll
  for (int i = 0; i < 3; ++i) {
    u16 tmp[HD];
#pragma unroll
    for (int d = 0; d < HD; ++d) tmp[d] = f2bf(acc[i][d]);
    u16* op = o + (row0 + i) * DIM + h * HD;
    *(short8v*)op = *(short8v*)tmp;
    *(short8v*)(op + 8) = *(short8v*)(tmp + 8);
  }
}

// ---------------- 128x128 MFMA GEMM, 8 waves (EXACT r4 winner) ------------------
// A[M][K] bf16, Bt[N][K] bf16. 512 threads (2M x 4N waves, wave tile 64x32);
// single-buffered 32 KiB LDS -> 3 blocks/CU (24 waves/CU). XOR swizzle
// byte^=((row&7)<<4) via pre-swizzled global source (linear global_load_lds
// dest) + swizzled ds_read. stage -> __syncthreads -> compute -> __syncthreads.
// (r5-r10 established: dbuf/ring/counted-vmcnt/64x64 all lose to this at K<=1536.)
// EPI 0: C bf16 plain
// EPI 1: resf bf16 = x + scatter(roll)   (outb=resf, residf=x)
// EPI 2: bias+ReLU bf16
// EPI 3: out fp32 = resf + acc + bias    (outf=out, residb=resf)
template<int EPI>
__global__ __launch_bounds__(512, 6) void gemm8w(const u16* __restrict__ A,
                                                 const u16* __restrict__ Bt,
                                                 int N, int K,
                                                 u16* __restrict__ outb,
                                                 float* __restrict__ outf,
                                                 const float* __restrict__ residf,
                                                 const u16* __restrict__ residb,
                                                 const float* __restrict__ bias) {
  __shared__ u16 As[128 * 64];
  __shared__ u16 Bs[128 * 64];
  const int tid = threadIdx.x;
  const int wave = tid >> 6, lane = tid & 63;
  const int wm = wave >> 2, wn = wave & 3;          // 2 M-waves x 4 N-waves
  const int r = lane & 15, gq = lane >> 4;

  // bijective XCD chunk swizzle (m204) on linearized bid (x fastest)
  const int nwg = gridDim.x, gx = N >> 7;
  int wg = blockIdx.x;
  int qd = nwg >> 3, rr = nwg & 7, xcd = wg & 7, lid = wg >> 3;
  int swz = (xcd < rr ? xcd * (qd + 1) : rr * (qd + 1) + (xcd - rr) * qd) + lid;
  const int tm = swz / gx, tn = swz - tm * gx;
  const int arow0 = tm * 128, brow0 = tn * 128;

  // staging precompute: 2 chunks of 8 KiB per matrix; linear LDS dest
  // d = c*8192 + tid*16 bytes, global source column pre-swizzled (same XOR).
  int srow[2], scol[2];
#pragma unroll
  for (int c = 0; c < 2; ++c) {
    int d = c * 8192 + tid * 16;
    srow[c] = d >> 7;
    scol[c] = (((d & 127) ^ ((srow[c] & 7) << 4)) >> 1);
  }

  // fragment-read swizzled K-offsets (elements); row&7 == r&7 (bases mult of 16)
  const int kx0 = (((gq * 16) ^ ((r & 7) << 4)) >> 1);        // kk = 0
  const int kx1 = (((64 + gq * 16) ^ ((r & 7) << 4)) >> 1);   // kk = 1
  const int rA = wm * 64 + r, rB = wn * 32 + r;

  float4v acc[4][2];
#pragma unroll
  for (int i = 0; i < 4; ++i)
#pragma unroll
    for (int j = 0; j < 2; ++j) acc[i][j] = (float4v){0.f, 0.f, 0.f, 0.f};

  const int NT = K >> 6;
  for (int t = 0; t < NT; ++t) {
    const int k0 = t << 6;
#pragma unroll
    for (int c = 0; c < 2; ++c) {
      gload_lds16(A  + (size_t)(arow0 + srow[c]) * K + k0 + scol[c],
                  &As[0] + c * 4096 + tid * 8);
      gload_lds16(Bt + (size_t)(brow0 + srow[c]) * K + k0 + scol[c],
                  &Bs[0] + c * 4096 + tid * 8);
    }
    __syncthreads();   // drains vmcnt(0): tile landed
#pragma unroll
    for (int kk = 0; kk < 2; ++kk) {
      const int kx = kk ? kx1 : kx0;
      short8v af[4], bfr[2];
#pragma unroll
      for (int i = 0; i < 4; ++i)
        af[i] = *(const short8v*)&As[(rA + i * 16) * 64 + kx];
#pragma unroll
      for (int j = 0; j < 2; ++j)
        bfr[j] = *(const short8v*)&Bs[(rB + j * 16) * 64 + kx];
#pragma unroll
      for (int i = 0; i < 4; ++i)
#pragma unroll
        for (int j = 0; j < 2; ++j)
          acc[i][j] = mfma_bf16(af[i], bfr[j], acc[i][j]);
    }
    __syncthreads();   // safe to overwrite buffer
  }

  // epilogue: D mapping col=lane&15, row=(lane>>4)*4+reg  [m89-verified]
#pragma unroll
  for (int i = 0; i < 4; ++i) {
#pragma unroll
    for (int j = 0; j < 2; ++j) {
      int colg = brow0 + wn * 32 + j * 16 + r;
      int rowb = arow0 + wm * 64 + i * 16 + gq * 4;
#pragma unroll
      for (int v = 0; v < 4; ++v) {
        int rg = rowb + v;
        float val = acc[i][j][v];
        if constexpr (EPI == 0) {
          outb[(size_t)rg * N + colg] = f2bf(val);
        } else if constexpr (EPI == 1) {
          if (rg < MREAL) {
            int b = rg / TP, m = rg - b * TP;
            int t = m + 1; if (t == TP) t = 0;
            if (t < TLEN) {
              size_t idx = ((size_t)b * TLEN + t) * DIM + colg;
              outb[idx] = f2bf(residf[idx] + val);
            }
          }
        } else if constexpr (EPI == 2) {
          float z = val + bias[colg];
          outb[(size_t)rg * N + colg] = f2bf(z > 0.f ? z : 0.f);
        } else {
          size_t idx = (size_t)rg * N + colg;
          outf[idx] = bf2f(residb[idx]) + val + bias[colg];
        }
      }
    }
  }
}

// ---------------- host ----------------
extern "C" void kernel_launch(void* const* d_in, const int* in_sizes, int n_in,
                              void* d_out, int out_size, void* d_ws, size_t ws_size,
                              hipStream_t stream) {
  const float* x      = (const float*)d_in[0];
  const float* g1     = (const float*)d_in[1];
  const float* b1     = (const float*)d_in[2];
  const float* w_qkv  = (const float*)d_in[3];
  const float* w_proj = (const float*)d_in[4];
  const float* g2     = (const float*)d_in[5];
  const float* b2     = (const float*)d_in[6];
  const float* w_mlp1 = (const float*)d_in[7];
  const float* b_mlp1 = (const float*)d_in[8];
  const float* w_mlp2 = (const float*)d_in[9];
  const float* b_mlp2 = (const float*)d_in[10];
  float* out = (float*)d_out;

  // workspace layout (~262 MB total)
  u16* xs     = (u16*)d_ws;                        // MP*768 bf16 (LN1, rolled/padded)
  u16* qkv    = xs     + (size_t)MP * DIM;         // MP*2304 bf16
  u16* obuf   = qkv    + (size_t)MP * 3 * DIM;     // MP*768 bf16 (attn out)
  u16* wqkvT  = obuf   + (size_t)MP * DIM;         // [2304][768]
  u16* wprojT = wqkvT  + (size_t)3 * DIM * DIM;    // [768][768]
  u16* wm1T   = wprojT + (size_t)DIM * DIM;        // [1536][768]
  u16* wm2T   = wm1T   + (size_t)2 * DIM * DIM;    // [768][1536]
  // region reuse across the pipeline (each producer runs after the consumer
  // of the previous tenant):
  u16* resf = xs;    // M2*768  bf16 residual trunk (xs dead after QKV GEMM)
  u16* ln2o = obuf;  // M2*768  (obuf dead after proj GEMM)
  u16* h1   = qkv;   // M2*1536 (qkv dead after attn)

  // LN1 + all weight transposes in one launch
  prep_kernel<<<LN_BLOCKS + NCVT, 256, 0, stream>>>(
      x, g1, b1, xs, w_qkv, w_proj, w_mlp1, w_mlp2, wqkvT, wprojT, wm1T, wm2T);

  gemm8w<0><<<(MP / 128) * (3 * DIM / 128), 512, 0, stream>>>(
      xs, wqkvT, 3 * DIM, DIM, qkv, nullptr, nullptr, nullptr, nullptr);

  attn_kernel<<<(BATCH * NWIN * HEADS) / 256, 256, 0, stream>>>(qkv, obuf);

  // proj: resf = bf16(x + scatter(attn @ w_proj))
  gemm8w<1><<<(MP / 128) * (DIM / 128), 512, 0, stream>>>(
      obuf, wprojT, DIM, DIM, resf, nullptr, x, nullptr, nullptr);

  lnb_kernel<<<M2 / 4, 256, 0, stream>>>(resf, g2, b2, ln2o);

  gemm8w<2><<<(M2 / 128) * (2 * DIM / 128), 512, 0, stream>>>(
      ln2o, wm1T, 2 * DIM, DIM, h1, nullptr, nullptr, nullptr, b_mlp1);

  // mlp2: out(fp32) = resf + h1 @ w_mlp2 + b
  gemm8w<3><<<(M2 / 128) * (DIM / 128), 512, 0, stream>>>(
      h1, wm2T, DIM, 2 * DIM, nullptr, out, nullptr, resf, b_mlp2);
}